// Round 1
// baseline (179.968 us; speedup 1.0000x reference)
//
#include <hip/hip_runtime.h>

#define H 256
#define NB 2048
#define BATCH 8

typedef unsigned short u16;
using bf16x8 = __attribute__((ext_vector_type(8))) __bf16;
using f32x4  = __attribute__((ext_vector_type(4))) float;

__device__ __forceinline__ u16 f2bf(float f) {
    union { float f; unsigned u; } v; v.f = f;
    unsigned r = v.u + 0x7fffu + ((v.u >> 16) & 1u);  // RNE
    return (u16)(r >> 16);
}

// ---- x (fp32, 16384x256) -> bf16 ----
__global__ void cvt_x_kernel(const float* __restrict__ x, u16* __restrict__ xbf) {
    int i = (blockIdx.x * 256 + threadIdx.x) * 4;
    float4 v = *(const float4*)(x + i);
    ushort4 o;
    o.x = f2bf(v.x); o.y = f2bf(v.y); o.z = f2bf(v.z); o.w = f2bf(v.w);
    *(ushort4*)(xbf + i) = o;
}

// ---- Wq^T, Wk^T -> bf16 (Wt[n][k] = W[k][n]) ----
__global__ void tw_kernel(const float* __restrict__ Wq, const float* __restrict__ Wk,
                          u16* __restrict__ wqt, u16* __restrict__ wkt) {
    int n = blockIdx.x, k = threadIdx.x;
    const float* W = blockIdx.y ? Wk : Wq;
    u16* o = blockIdx.y ? wkt : wqt;
    o[n * H + k] = f2bf(W[k * H + n]);
}

// ---- wvw[i] = sum_j Wv[i][j] * Ww[j]  (fp32) ----
__global__ void wvw_kernel(const float* __restrict__ Wv, const float* __restrict__ Ww,
                           float* __restrict__ wvw) {
    int i = threadIdx.x;
    float s = 0.f;
    for (int j = 0; j < H; ++j) s += Wv[i * H + j] * Ww[j];
    wvw[i] = s;
}

// ---- u[row] = x[row]·wvw + bv·Ww  (fp32, one wave per row) ----
__global__ void u_kernel(const float* __restrict__ x, const float* __restrict__ wvw,
                         const float* __restrict__ bv, const float* __restrict__ Ww,
                         float* __restrict__ u) {
    int lane = threadIdx.x & 63;
    int row  = blockIdx.x * 4 + (threadIdx.x >> 6);
    float4 xv = *(const float4*)(x + row * H + lane * 4);
    float4 wv = *(const float4*)(wvw + lane * 4);
    float s = xv.x * wv.x + xv.y * wv.y + xv.z * wv.z + xv.w * wv.w;
    float4 bvv = *(const float4*)(bv + lane * 4);
    float4 www = *(const float4*)(Ww + lane * 4);
    float c = bvv.x * www.x + bvv.y * www.y + bvv.z * www.z + bvv.w * www.w;
    for (int o = 32; o; o >>= 1) { s += __shfl_xor(s, o); c += __shfl_xor(c, o); }
    if (lane == 0) u[row] = s + c;
}

// ---- q = (x@Wq + bq)/16, k = x@Wk + bk  (bf16 out, MFMA 16x16x32) ----
__global__ __launch_bounds__(256) void proj_kernel(
        const u16* __restrict__ xbf, const u16* __restrict__ wqt, const u16* __restrict__ wkt,
        const float* __restrict__ bq, const float* __restrict__ bk,
        u16* __restrict__ qbf, u16* __restrict__ kbf) {
    __shared__ u16 bt[64 * 264];  // 64 n-rows x 256 k, pad +8 to break bank stride
    const u16* wt      = blockIdx.z ? wkt : wqt;
    const float* bias  = blockIdx.z ? bk : bq;
    u16* outp          = blockIdx.z ? kbf : qbf;
    const float sc     = blockIdx.z ? 1.0f : 0.0625f;  // fold 1/sqrt(256) into q

    int tid = threadIdx.x;
    int mb = blockIdx.x * 64, nb = blockIdx.y * 64;

    for (int it = 0; it < 8; ++it) {
        int c = it * 256 + tid;
        int row = c >> 5, col = (c & 31) * 8;
        *(uint4*)&bt[row * 264 + col] = *(const uint4*)(wt + (nb + row) * H + col);
    }
    __syncthreads();

    int w = tid >> 6, lane = tid & 63;
    int l15 = lane & 15, quad = lane >> 4;

    bf16x8 a[8];
    const u16* abase = xbf + (mb + w * 16 + l15) * H + quad * 8;
    for (int ks = 0; ks < 8; ++ks) a[ks] = *(const bf16x8*)(abase + ks * 32);

    f32x4 acc[4] = {};
    for (int ks = 0; ks < 8; ++ks)
        for (int t = 0; t < 4; ++t) {
            bf16x8 b = *(const bf16x8*)&bt[(t * 16 + l15) * 264 + ks * 32 + quad * 8];
            acc[t] = __builtin_amdgcn_mfma_f32_16x16x32_bf16(a[ks], b, acc[t], 0, 0, 0);
        }

    int m = mb + w * 16 + quad * 4;
    for (int t = 0; t < 4; ++t) {
        int n = nb + t * 16 + l15;
        float bsn = bias[n];
        for (int r = 0; r < 4; ++r)
            outp[(m + r) * H + n] = f2bf((acc[t][r] + bsn) * sc);
    }
}

// ---- flash attention with scalar value u: out = softmax(q k^T)@u + bw ----
__global__ __launch_bounds__(256) void attn_kernel(
        const u16* __restrict__ qbf, const u16* __restrict__ kbf,
        const float* __restrict__ u, const float* __restrict__ bw,
        float* __restrict__ out) {
    __shared__ u16 kt[64 * 264];
    __shared__ float ut[64];
    int tid = threadIdx.x;
    int b = blockIdx.y, qb = blockIdx.x * 64;
    int w = tid >> 6, lane = tid & 63, l15 = lane & 15, quad = lane >> 4;

    bf16x8 aq[8];
    const u16* qbase = qbf + (size_t)(b * NB + qb + w * 16 + l15) * H + quad * 8;
    for (int ks = 0; ks < 8; ++ks) aq[ks] = *(const bf16x8*)(qbase + ks * 32);

    float ms[4] = {-1e30f, -1e30f, -1e30f, -1e30f};
    float ls[4] = {0.f, 0.f, 0.f, 0.f};
    float as[4] = {0.f, 0.f, 0.f, 0.f};

    for (int kb = 0; kb < NB; kb += 64) {
        const u16* ksrc = kbf + (size_t)(b * NB + kb) * H;
        for (int it = 0; it < 8; ++it) {
            int c = it * 256 + tid;
            int row = c >> 5, col = (c & 31) * 8;
            *(uint4*)&kt[row * 264 + col] = *(const uint4*)(ksrc + row * H + col);
        }
        if (tid < 64) ut[tid] = u[b * NB + kb + tid];
        __syncthreads();

        f32x4 acc[4] = {};
        for (int ks = 0; ks < 8; ++ks)
            for (int t = 0; t < 4; ++t) {
                bf16x8 bfr = *(const bf16x8*)&kt[(t * 16 + l15) * 264 + ks * 32 + quad * 8];
                acc[t] = __builtin_amdgcn_mfma_f32_16x16x32_bf16(aq[ks], bfr, acc[t], 0, 0, 0);
            }

        float uv[4];
        for (int t = 0; t < 4; ++t) uv[t] = ut[t * 16 + l15];

        for (int r = 0; r < 4; ++r) {
            float rmax = fmaxf(fmaxf(acc[0][r], acc[1][r]), fmaxf(acc[2][r], acc[3][r]));
            for (int o = 1; o < 16; o <<= 1) rmax = fmaxf(rmax, __shfl_xor(rmax, o));
            float mnew = fmaxf(ms[r], rmax);
            float p0 = __expf(acc[0][r] - mnew), p1 = __expf(acc[1][r] - mnew);
            float p2 = __expf(acc[2][r] - mnew), p3 = __expf(acc[3][r] - mnew);
            float sp = p0 + p1 + p2 + p3;
            float su = p0 * uv[0] + p1 * uv[1] + p2 * uv[2] + p3 * uv[3];
            for (int o = 1; o < 16; o <<= 1) { sp += __shfl_xor(sp, o); su += __shfl_xor(su, o); }
            float alpha = __expf(ms[r] - mnew);
            ls[r] = ls[r] * alpha + sp;
            as[r] = as[r] * alpha + su;
            ms[r] = mnew;
        }
        __syncthreads();
    }

    if (l15 == 0) {
        float bw0 = bw[0];
        for (int r = 0; r < 4; ++r)
            out[b * NB + qb + w * 16 + quad * 4 + r] = as[r] / ls[r] + bw0;
    }
}

extern "C" void kernel_launch(void* const* d_in, const int* in_sizes, int n_in,
                              void* d_out, int out_size, void* d_ws, size_t ws_size,
                              hipStream_t stream) {
    (void)in_sizes; (void)n_in; (void)out_size; (void)ws_size;
    const float* x  = (const float*)d_in[0];
    const float* Wq = (const float*)d_in[1];
    const float* bq = (const float*)d_in[2];
    const float* Wk = (const float*)d_in[3];
    const float* bk = (const float*)d_in[4];
    const float* Wv = (const float*)d_in[5];
    const float* bv = (const float*)d_in[6];
    const float* Ww = (const float*)d_in[7];
    const float* bw = (const float*)d_in[8];
    float* out = (float*)d_out;

    u16* xbf = (u16*)d_ws;                 // 4194304 u16
    u16* qbf = xbf + 4194304;              // 4194304 u16
    u16* kbf = qbf + 4194304;              // 4194304 u16
    u16* wqt = kbf + 4194304;              // 65536 u16
    u16* wkt = wqt + 65536;                // 65536 u16
    float* wvw = (float*)(wkt + 65536);    // 256 f32
    float* uu  = wvw + 256;                // 16384 f32  (total ~25.5 MB)

    hipLaunchKernelGGL(cvt_x_kernel, dim3(4096), dim3(256), 0, stream, x, xbf);
    hipLaunchKernelGGL(tw_kernel, dim3(256, 2), dim3(256), 0, stream, Wq, Wk, wqt, wkt);
    hipLaunchKernelGGL(wvw_kernel, dim3(1), dim3(256), 0, stream, Wv, Ww, wvw);
    hipLaunchKernelGGL(u_kernel, dim3(4096), dim3(256), 0, stream, x, wvw, bv, Ww, uu);
    hipLaunchKernelGGL(proj_kernel, dim3(256, 4, 2), dim3(256), 0, stream,
                       xbf, wqt, wkt, bq, bk, qbf, kbf);
    hipLaunchKernelGGL(attn_kernel, dim3(32, 8), dim3(256), 0, stream, qbf, kbf, uu, bw, out);
}

// Round 2
// 129.351 us; speedup vs baseline: 1.3913x; 1.3913x over previous
//
#include <hip/hip_runtime.h>

#define H 256
#define NB 2048
#define BATCH 8
#define NSPLIT 4
#define KSPAN (NB / NSPLIT)   // 512 keys per split

typedef unsigned short u16;
using bf16x8 = __attribute__((ext_vector_type(8))) __bf16;
using f32x4  = __attribute__((ext_vector_type(4))) float;

__device__ __forceinline__ u16 f2bf(float f) {
    union { float f; unsigned u; } v; v.f = f;
    unsigned r = v.u + 0x7fffu + ((v.u >> 16) & 1u);  // RNE
    return (u16)(r >> 16);
}

// ---- weight prep: Wq^T,Wk^T -> bf16; wvw = Wv@Ww (fp32). One block per n. ----
__global__ __launch_bounds__(256) void weights_kernel(
        const float* __restrict__ Wq, const float* __restrict__ Wk,
        const float* __restrict__ Wv, const float* __restrict__ Ww,
        u16* __restrict__ wqt, u16* __restrict__ wkt, float* __restrict__ wvw) {
    int n = blockIdx.x, k = threadIdx.x;
    wqt[n * H + k] = f2bf(Wq[k * H + n]);
    wkt[n * H + k] = f2bf(Wk[k * H + n]);
    float p = Wv[n * H + k] * Ww[k];
    for (int o = 32; o; o >>= 1) p += __shfl_xor(p, o);
    __shared__ float red[4];
    int w = threadIdx.x >> 6, lane = threadIdx.x & 63;
    if (lane == 0) red[w] = p;
    __syncthreads();
    if (threadIdx.x == 0) wvw[n] = red[0] + red[1] + red[2] + red[3];
}

// ---- x -> bf16, fused with u[row] = x[row]·wvw + bv·Ww. One wave per row. ----
__global__ __launch_bounds__(256) void cvtu_kernel(
        const float* __restrict__ x, const float* __restrict__ wvw,
        const float* __restrict__ bv, const float* __restrict__ Ww,
        u16* __restrict__ xbf, float* __restrict__ uu) {
    int lane = threadIdx.x & 63;
    int row  = blockIdx.x * 4 + (threadIdx.x >> 6);
    float4 xv = *(const float4*)(x + row * H + lane * 4);
    ushort4 o;
    o.x = f2bf(xv.x); o.y = f2bf(xv.y); o.z = f2bf(xv.z); o.w = f2bf(xv.w);
    *(ushort4*)(xbf + row * H + lane * 4) = o;
    float4 wv = *(const float4*)(wvw + lane * 4);
    float s = xv.x * wv.x + xv.y * wv.y + xv.z * wv.z + xv.w * wv.w;
    float4 bvv = *(const float4*)(bv + lane * 4);
    float4 www = *(const float4*)(Ww + lane * 4);
    float c = bvv.x * www.x + bvv.y * www.y + bvv.z * www.z + bvv.w * www.w;
    for (int o2 = 32; o2; o2 >>= 1) { s += __shfl_xor(s, o2); c += __shfl_xor(c, o2); }
    if (lane == 0) uu[row] = s + c;
}

// ---- q = (x@Wq + bq)/16, k = x@Wk + bk  (bf16 out, MFMA 16x16x32) ----
__global__ __launch_bounds__(256) void proj_kernel(
        const u16* __restrict__ xbf, const u16* __restrict__ wqt, const u16* __restrict__ wkt,
        const float* __restrict__ bq, const float* __restrict__ bk,
        u16* __restrict__ qbf, u16* __restrict__ kbf) {
    __shared__ u16 bt[64 * 264];
    const u16* wt      = blockIdx.z ? wkt : wqt;
    const float* bias  = blockIdx.z ? bk : bq;
    u16* outp          = blockIdx.z ? kbf : qbf;
    const float sc     = blockIdx.z ? 1.0f : 0.0625f;  // fold 1/sqrt(256) into q

    int tid = threadIdx.x;
    int mb = blockIdx.x * 64, nb = blockIdx.y * 64;

    for (int it = 0; it < 8; ++it) {
        int c = it * 256 + tid;
        int row = c >> 5, col = (c & 31) * 8;
        *(uint4*)&bt[row * 264 + col] = *(const uint4*)(wt + (nb + row) * H + col);
    }
    __syncthreads();

    int w = tid >> 6, lane = tid & 63;
    int l15 = lane & 15, quad = lane >> 4;

    bf16x8 a[8];
    const u16* abase = xbf + (mb + w * 16 + l15) * H + quad * 8;
    for (int ks = 0; ks < 8; ++ks) a[ks] = *(const bf16x8*)(abase + ks * 32);

    f32x4 acc[4] = {};
    for (int ks = 0; ks < 8; ++ks)
        for (int t = 0; t < 4; ++t) {
            bf16x8 b = *(const bf16x8*)&bt[(t * 16 + l15) * 264 + ks * 32 + quad * 8];
            acc[t] = __builtin_amdgcn_mfma_f32_16x16x32_bf16(a[ks], b, acc[t], 0, 0, 0);
        }

    int m = mb + w * 16 + quad * 4;
    for (int t = 0; t < 4; ++t) {
        int n = nb + t * 16 + l15;
        float bsn = bias[n];
        for (int r = 0; r < 4; ++r)
            outp[(m + r) * H + n] = f2bf((acc[t][r] + bsn) * sc);
    }
}

// ---- attention, K-split. No max-subtraction (|logit| < ~2): plain exp sums. ----
__global__ __launch_bounds__(256) void attn_kernel(
        const u16* __restrict__ qbf, const u16* __restrict__ kbf,
        const float* __restrict__ u,
        float* __restrict__ pnum, float* __restrict__ pden) {
    __shared__ u16 kt[64 * 264];
    __shared__ float ut[64];
    int tid = threadIdx.x;
    int b = blockIdx.y, qb = blockIdx.x * 64, sp = blockIdx.z;
    int w = tid >> 6, lane = tid & 63, l15 = lane & 15, quad = lane >> 4;

    bf16x8 aq[8];
    const u16* qbase = qbf + (size_t)(b * NB + qb + w * 16 + l15) * H + quad * 8;
    for (int ks = 0; ks < 8; ++ks) aq[ks] = *(const bf16x8*)(qbase + ks * 32);

    float ls[4] = {0.f, 0.f, 0.f, 0.f};   // per-lane partial denominators
    float as[4] = {0.f, 0.f, 0.f, 0.f};   // per-lane partial numerators

    const int kb0 = sp * KSPAN;
    for (int kb = kb0; kb < kb0 + KSPAN; kb += 64) {
        const u16* ksrc = kbf + (size_t)(b * NB + kb) * H;
        for (int it = 0; it < 8; ++it) {
            int c = it * 256 + tid;
            int row = c >> 5, col = (c & 31) * 8;
            *(uint4*)&kt[row * 264 + col] = *(const uint4*)(ksrc + row * H + col);
        }
        if (tid < 64) ut[tid] = u[b * NB + kb + tid];
        __syncthreads();

        f32x4 acc[4] = {};
        for (int ks = 0; ks < 8; ++ks)
            for (int t = 0; t < 4; ++t) {
                bf16x8 bfr = *(const bf16x8*)&kt[(t * 16 + l15) * 264 + ks * 32 + quad * 8];
                acc[t] = __builtin_amdgcn_mfma_f32_16x16x32_bf16(aq[ks], bfr, acc[t], 0, 0, 0);
            }

        float uv[4];
        for (int t = 0; t < 4; ++t) uv[t] = ut[t * 16 + l15];

        // no cross-lane ops here — pure per-lane accumulation
        for (int r = 0; r < 4; ++r) {
            float p0 = __expf(acc[0][r]), p1 = __expf(acc[1][r]);
            float p2 = __expf(acc[2][r]), p3 = __expf(acc[3][r]);
            ls[r] += (p0 + p1) + (p2 + p3);
            as[r] += (p0 * uv[0] + p1 * uv[1]) + (p2 * uv[2] + p3 * uv[3]);
        }
        __syncthreads();
    }

    // one deferred 16-lane (l15) reduction per row
    for (int r = 0; r < 4; ++r) {
        for (int o = 1; o < 16; o <<= 1) {
            ls[r] += __shfl_xor(ls[r], o);
            as[r] += __shfl_xor(as[r], o);
        }
    }
    if (l15 == 0) {
        size_t base = (size_t)(sp * BATCH + b) * NB + qb + w * 16 + quad * 4;
        for (int r = 0; r < 4; ++r) {
            pnum[base + r] = as[r];
            pden[base + r] = ls[r];
        }
    }
}

// ---- combine K-splits: out = sum(num)/sum(den) + bw ----
__global__ __launch_bounds__(256) void finalize_kernel(
        const float* __restrict__ pnum, const float* __restrict__ pden,
        const float* __restrict__ bw, float* __restrict__ out) {
    int i = blockIdx.x * 256 + threadIdx.x;   // i = b*NB + n
    float num = 0.f, den = 0.f;
    for (int sp = 0; sp < NSPLIT; ++sp) {
        num += pnum[sp * (BATCH * NB) + i];
        den += pden[sp * (BATCH * NB) + i];
    }
    out[i] = num / den + bw[0];
}

extern "C" void kernel_launch(void* const* d_in, const int* in_sizes, int n_in,
                              void* d_out, int out_size, void* d_ws, size_t ws_size,
                              hipStream_t stream) {
    (void)in_sizes; (void)n_in; (void)out_size; (void)ws_size;
    const float* x  = (const float*)d_in[0];
    const float* Wq = (const float*)d_in[1];
    const float* bq = (const float*)d_in[2];
    const float* Wk = (const float*)d_in[3];
    const float* bk = (const float*)d_in[4];
    const float* Wv = (const float*)d_in[5];
    const float* bv = (const float*)d_in[6];
    const float* Ww = (const float*)d_in[7];
    const float* bw = (const float*)d_in[8];
    float* out = (float*)d_out;

    u16* xbf = (u16*)d_ws;                 // 4194304 u16
    u16* qbf = xbf + 4194304;              // 4194304 u16
    u16* kbf = qbf + 4194304;              // 4194304 u16
    u16* wqt = kbf + 4194304;              // 65536 u16
    u16* wkt = wqt + 65536;                // 65536 u16
    float* wvw  = (float*)(wkt + 65536);   // 256 f32
    float* uu   = wvw + 256;               // 16384 f32
    float* pnum = uu + 16384;              // 4*16384 f32
    float* pden = pnum + NSPLIT * BATCH * NB;  // 4*16384 f32

    hipLaunchKernelGGL(weights_kernel, dim3(256), dim3(256), 0, stream,
                       Wq, Wk, Wv, Ww, wqt, wkt, wvw);
    hipLaunchKernelGGL(cvtu_kernel, dim3(4096), dim3(256), 0, stream,
                       x, wvw, bv, Ww, xbf, uu);
    hipLaunchKernelGGL(proj_kernel, dim3(256, 4, 2), dim3(256), 0, stream,
                       xbf, wqt, wkt, bq, bk, qbf, kbf);
    hipLaunchKernelGGL(attn_kernel, dim3(32, 8, NSPLIT), dim3(256), 0, stream,
                       qbf, kbf, uu, pnum, pden);
    hipLaunchKernelGGL(finalize_kernel, dim3(64), dim3(256), 0, stream,
                       pnum, pden, bw, out);
}